// Round 9
// baseline (256.476 us; speedup 1.0000x reference)
//
#include <hip/hip_runtime.h>
#include <hip/hip_bf16.h>

#define N_NODES 50000
#define N_RELS 8
#define IN_DIM 128
#define OUT_DIM 128
#define N_EDGES 800000
#define NR (N_NODES * N_RELS)              /* 400000 keys (tgt*8+rel) */
#define KDIM (N_RELS * IN_DIM)             /* 1024 = GEMM K */
#define SCAN_ELEMS 2048
#define SCAN_NBLK ((NR + SCAN_ELEMS - 1) / SCAN_ELEMS)  /* 196 */
#define FUSE_BLKS 1563                     /* 1563 * 32 = 50016 >= N_NODES */
#define CNT_BLKS ((N_EDGES / 4 + 255) / 256)   /* 782 */
#define CW_BLKS ((N_RELS * IN_DIM * OUT_DIM + 255) / 256) /* 512 */
#define FB_BLKS ((N_NODES * IN_DIM / 8 + 255) / 256)      /* 3125 */

typedef __attribute__((ext_vector_type(8))) short bf16x8;
typedef __attribute__((ext_vector_type(4))) float floatx4;
typedef __attribute__((ext_vector_type(4))) unsigned int uintx4;

__device__ inline unsigned short f2bf(float f) {
    unsigned u = __builtin_bit_cast(unsigned, f);
    u += 0x7fff + ((u >> 16) & 1);   // round-to-nearest-even
    return (unsigned short)(u >> 16);
}
__device__ inline float bflo(unsigned u) {   // low bf16 of a packed pair
    return __builtin_bit_cast(float, u << 16);
}
__device__ inline float bfhi(unsigned u) {   // high bf16 of a packed pair
    return __builtin_bit_cast(float, u & 0xffff0000u);
}

// ---------------- prep: histogram + W-conversion + feature-conversion ----------------
__global__ void prep_kernel(const int* __restrict__ tri, const float* __restrict__ W,
                            const float* __restrict__ features,
                            int* __restrict__ cnt, unsigned short* __restrict__ Wtf,
                            unsigned short* __restrict__ featB) {
    const int b = blockIdx.x;
    if (b < CNT_BLKS) {
        int t = b * 256 + threadIdx.x;
        if (t >= N_EDGES / 4) return;
        const int4* tri4 = (const int4*)tri;
        int4 a = tri4[3 * t], v = tri4[3 * t + 1], c = tri4[3 * t + 2];
        // edges: (a.x,a.y,a.z) (a.w,v.x,v.y) (v.z,v.w,c.x) (c.y,c.z,c.w)
        atomicAdd(&cnt[a.z * N_RELS + a.y], 1);
        atomicAdd(&cnt[v.y * N_RELS + v.x], 1);
        atomicAdd(&cnt[c.x * N_RELS + v.w], 1);
        atomicAdd(&cnt[c.w * N_RELS + c.z], 1);
    } else if (b < CNT_BLKS + CW_BLKS) {
        int idx = (b - CNT_BLKS) * 256 + threadIdx.x;   // 0 .. 131071
        if (idx >= N_RELS * IN_DIM * OUT_DIM) return;
        int e  = idx & 7;
        int l  = (idx >> 3) & 63;
        int ks = (idx >> 9) & 31;
        int nt = idx >> 14;
        int o = nt * 16 + (l & 15);
        int k = ks * 32 + (l >> 4) * 8 + e;             // global K index
        Wtf[idx] = f2bf(W[(k >> 7) * (IN_DIM * OUT_DIM) + (k & 127) * OUT_DIM + o]);
    } else {
        int t = (b - CNT_BLKS - CW_BLKS) * 256 + threadIdx.x;   // 8 floats each
        if (t >= N_NODES * IN_DIM / 8) return;
        const float4* f4 = (const float4*)features;
        float4 x = f4[2 * t], y = f4[2 * t + 1];
        uint4 o;
        o.x = (unsigned)f2bf(x.x) | ((unsigned)f2bf(x.y) << 16);
        o.y = (unsigned)f2bf(x.z) | ((unsigned)f2bf(x.w) << 16);
        o.z = (unsigned)f2bf(y.x) | ((unsigned)f2bf(y.y) << 16);
        o.w = (unsigned)f2bf(y.z) | ((unsigned)f2bf(y.w) << 16);
        ((uint4*)featB)[t] = o;
    }
}

// ---------------- 2-pass scan ----------------
__global__ void scan_part(const int* __restrict__ cnt, int* __restrict__ bsum) {
    __shared__ int s[256];
    int b = blockIdx.x, t = threadIdx.x;
    int base = b * SCAN_ELEMS + t * 8;
    int sum = 0;
#pragma unroll
    for (int k = 0; k < 8; ++k) {
        int i = base + k;
        sum += (i < NR) ? cnt[i] : 0;
    }
    s[t] = sum; __syncthreads();
    for (int off = 128; off > 0; off >>= 1) {
        if (t < off) s[t] += s[t + off];
        __syncthreads();
    }
    if (t == 0) bsum[b] = s[0];
}

__global__ __launch_bounds__(256) void scan_fused(
    const int* __restrict__ cnt, const int* __restrict__ bsum,
    int* __restrict__ segOff, int* __restrict__ cursor)
{
    __shared__ int s[256];
    __shared__ int sboff;
    const int b = blockIdx.x, t = threadIdx.x;

    // phase 1: scan the 196 per-block sums; this block's exclusive base
    int vb = (t < SCAN_NBLK) ? bsum[t] : 0;
    s[t] = vb; __syncthreads();
    for (int off = 1; off < 256; off <<= 1) {
        int x = (t >= off) ? s[t - off] : 0;
        __syncthreads();
        s[t] += x;
        __syncthreads();
    }
    if (t == 0) sboff = (b == 0) ? 0 : s[b - 1];
    __syncthreads();
    const int boff = sboff;

    // phase 2: per-element scan of this block's 2048 counters
    const int base = b * SCAN_ELEMS + t * 8;
    int v[8]; int sum = 0;
#pragma unroll
    for (int k = 0; k < 8; ++k) {
        int i = base + k;
        v[k] = (i < NR) ? cnt[i] : 0;
        sum += v[k];
    }
    s[t] = sum; __syncthreads();
    for (int off = 1; off < 256; off <<= 1) {
        int x = (t >= off) ? s[t - off] : 0;
        __syncthreads();
        s[t] += x;
        __syncthreads();
    }
    int run = boff + s[t] - sum;   // exclusive offset for this thread's chunk
#pragma unroll
    for (int k = 0; k < 8; ++k) {
        int i = base + k;
        if (i < NR) { segOff[i] = run; cursor[i] = run; run += v[k]; }
    }
    if (b == 0 && t == 0) segOff[NR] = N_EDGES;
}

// ---------------- scatter: 4 edges per thread via int4 ----------------
// R17: the atomicAdd->dependent-store chain was 1-deep per thread; now 4
// independent chains per thread (4x MLP), 1/4 the threads, 16-B loads.
// Within-segment edge order changes — sum is commutative, no correctness
// impact.
__global__ void scatter_kernel(const int* __restrict__ tri, int* __restrict__ cursor,
                               int* __restrict__ sortedSrc) {
    int t = blockIdx.x * 256 + threadIdx.x;
    if (t >= N_EDGES / 4) return;
    const int4* tri4 = (const int4*)tri;
    int4 a = tri4[3 * t], v = tri4[3 * t + 1], c = tri4[3 * t + 2];
    // edges: (a.x,a.y,a.z) (a.w,v.x,v.y) (v.z,v.w,c.x) (c.y,c.z,c.w)
    int p0 = atomicAdd(&cursor[a.z * N_RELS + a.y], 1);
    int p1 = atomicAdd(&cursor[v.y * N_RELS + v.x], 1);
    int p2 = atomicAdd(&cursor[c.x * N_RELS + v.w], 1);
    int p3 = atomicAdd(&cursor[c.w * N_RELS + c.z], 1);
    sortedSrc[p0] = a.x;
    sortedSrc[p1] = a.w;
    sortedSrc[p2] = v.z;
    sortedSrc[p3] = c.y;
}

// ---------------- fused agg + GEMM ----------------
// R13: fusion killed the 205 MB aggG round trip. R14: M=32 -> 4 blk/CU,
// occ 64% (best fused: 83.5 us). R15/R16 regressions reverted: gather is
// the r6-exact unroll-2 loop, no descriptor prefetch. R17 keeps only r8's
// verified full-line epilogue: acc -> LDS re-layout -> NT floatx4 stores
// (lane = 32 B contiguous, wave = full lines) -> no RFO, no partial-line
// NT churn. Clean A/B vs r8: if WRITE collapses ~90->27 MB, r8's bloat was
// the unroll-4 gather (spills), not the epilogue.
__global__ __launch_bounds__(512, 8) void fused_kernel(
    const int* __restrict__ sortedSrc, const int* __restrict__ segOff,
    const unsigned short* __restrict__ featB,
    const unsigned short* __restrict__ Wtf,
    const float* __restrict__ bias,
    float* __restrict__ out)
{
    __shared__ __align__(16) unsigned short Atile[32 * 512]; // 32 KB
    const int tid = threadIdx.x;
    const int wave = tid >> 6, lane = tid & 63;
    const int q = lane >> 4, l16 = lane & 15;    // quarter / lane-in-quarter
    const int m0 = blockIdx.x * 32;
    const int wm = wave & 1, wn = wave >> 1;     // 2 (M) x 4 (N) wave grid

    floatx4 acc[2];
#pragma unroll
    for (int nt = 0; nt < 2; ++nt) acc[nt] = (floatx4){0.f, 0.f, 0.f, 0.f};

    const unsigned short* fb = featB + 8 * l16;  // dims 8*l16 .. 8*l16+7

#pragma unroll
    for (int p = 0; p < 2; ++p) {
        // ---- agg phase: 4 nodes per wave, quarter q handles rel 4p+q ----
        for (int i = 0; i < 4; ++i) {
            const int nl = wave * 4 + i;         // local row 0..31
            const int node = m0 + nl;
            if (node < N_NODES) {
                int bnd = 0;
                if (lane < 5) bnd = segOff[node * N_RELS + 4 * p + lane];
                int sg[5];
#pragma unroll
                for (int k = 0; k < 5; ++k) sg[k] = __shfl(bnd, k);

                const int e0 = sg[0], eN = sg[4];
                int srcw = 0;
                if (e0 + lane < eN) srcw = sortedSrc[e0 + lane];  // 64-src window

                const int s0v = sg[q], s1v = sg[q + 1];
                const int len = s1v - s0v;
                int m0x = __shfl_xor(len, 16);               // full exec
                int jm = (len > m0x) ? len : m0x;
                int m1x = __shfl_xor(jm, 32);                // full exec
                const int jmax = (jm > m1x) ? jm : m1x;      // wave-uniform
                float a0 = 0.f, a1 = 0.f, a2 = 0.f, a3 = 0.f;
                float a4 = 0.f, a5 = 0.f, a6 = 0.f, a7 = 0.f;
                for (int j = 0; j < jmax; j += 2) {          // uniform trips
                    const int ea = s0v + j;
                    const int ia = ea - e0;
                    const int swina = __shfl(srcw, ia & 63); // full exec
                    const int ib = ia + 1;
                    const int swinb = __shfl(srcw, ib & 63); // full exec
                    const bool pa = j < len;
                    const bool pb = j + 1 < len;
                    int srca = 0, srcb = 0;
                    if (pa) srca = (ia < 64) ? swina : sortedSrc[ea];
                    if (pb) srcb = (ib < 64) ? swinb : sortedSrc[ea + 1];
                    uint4 ua = *(const uint4*)&fb[srca * IN_DIM];
                    uint4 ub = *(const uint4*)&fb[srcb * IN_DIM];
                    if (pa) {
                        a0 += bflo(ua.x); a1 += bfhi(ua.x);
                        a2 += bflo(ua.y); a3 += bfhi(ua.y);
                        a4 += bflo(ua.z); a5 += bfhi(ua.z);
                        a6 += bflo(ua.w); a7 += bfhi(ua.w);
                    }
                    if (pb) {
                        a0 += bflo(ub.x); a1 += bfhi(ub.x);
                        a2 += bflo(ub.y); a3 += bfhi(ub.y);
                        a4 += bflo(ub.z); a5 += bfhi(ub.z);
                        a6 += bflo(ub.w); a7 += bfhi(ub.w);
                    }
                }
                const float inv = (len > 0) ? 1.0f / (float)len : 0.0f;
                uintx4 pk;
                pk[0] = (unsigned)f2bf(a0 * inv) | ((unsigned)f2bf(a1 * inv) << 16);
                pk[1] = (unsigned)f2bf(a2 * inv) | ((unsigned)f2bf(a3 * inv) << 16);
                pk[2] = (unsigned)f2bf(a4 * inv) | ((unsigned)f2bf(a5 * inv) << 16);
                pk[3] = (unsigned)f2bf(a6 * inv) | ((unsigned)f2bf(a7 * inv) << 16);
                // unit u = q*16+l16 holds cols u*8..u*8+7; XOR-swizzle by row
                const int us = (q * 16 + l16) ^ (nl & 15);
                *(uintx4*)&Atile[(nl * 64 + us) * 8] = pk;
            }
        }
        __syncthreads();                 // A-tile chunk visible

        // ---- GEMM phase: K-chunk p (512 cols), wave-tile 16x32 ----
        __builtin_amdgcn_s_setprio(1);
#pragma unroll
        for (int ksl = 0; ksl < 16; ++ksl) {
            const int ks = p * 16 + ksl;             // global k-slice
            const int r = wm * 16 + l16;
            const int us = (ksl * 4 + q) ^ (r & 15);
            bf16x8 a = *(const bf16x8*)&Atile[(r * 64 + us) * 8];
#pragma unroll
            for (int nt = 0; nt < 2; ++nt) {
                const int ntg = wn * 2 + nt;
                bf16x8 b = *(const bf16x8*)&Wtf[(size_t)((ntg * 32 + ks) * 64 + lane) * 8];
                acc[nt] = __builtin_amdgcn_mfma_f32_16x16x32_bf16(a, b, acc[nt], 0, 0, 0);
            }
        }
        __builtin_amdgcn_s_setprio(0);
        __syncthreads();                 // reads done before next pass writes
    }

    // ---- epilogue: acc -> LDS (D-layout scatter) -> full-line NT stores ----
    float* fbuf = (float*)Atile;     // 32 rows x 128 f32 = 16 KB
#pragma unroll
    for (int nt = 0; nt < 2; ++nt) {
        const int o = (wn * 2 + nt) * 16 + l16;
        const float bv = bias[o];
#pragma unroll
        for (int j = 0; j < 4; ++j) {
            const int r = wm * 16 + q * 4 + j;   // local row 0..31
            fbuf[r * 128 + o] = acc[nt][j] + bv;
        }
    }
    __syncthreads();
    {
        const int row = tid >> 4;            // 0..31
        const int col = (tid & 15) * 8;      // 0..120
        const int node = m0 + row;
        if (node < N_NODES) {
            floatx4 w0 = *(const floatx4*)&fbuf[row * 128 + col];
            floatx4 w1 = *(const floatx4*)&fbuf[row * 128 + col + 4];
            float* po = &out[(size_t)node * OUT_DIM + col];
            __builtin_nontemporal_store(w0, (floatx4*)po);
            __builtin_nontemporal_store(w1, (floatx4*)(po + 4));
        }
    }
}

extern "C" void kernel_launch(void* const* d_in, const int* in_sizes, int n_in,
                              void* d_out, int out_size, void* d_ws, size_t ws_size,
                              hipStream_t stream)
{
    const int*   tri      = (const int*)d_in[0];
    const float* features = (const float*)d_in[1];
    const float* W        = (const float*)d_in[2];
    const float* bias     = (const float*)d_in[3];
    float* out = (float*)d_out;

    char* ws = (char*)d_ws;
    unsigned short* Wtf = (unsigned short*)ws; ws += (size_t)OUT_DIM * KDIM * 2;  // 256 KB
    int* cnt       = (int*)ws; ws += (size_t)NR * 4;
    int* segOff    = (int*)ws; ws += (size_t)(NR + 4) * 4;
    int* cursor    = (int*)ws; ws += (size_t)NR * 4;
    int* bsum      = (int*)ws; ws += (size_t)SCAN_NBLK * 4;
    int* sortedSrc = (int*)ws; ws += (size_t)N_EDGES * 4;
    unsigned short* featB = (unsigned short*)ws; ws += (size_t)N_NODES * IN_DIM * 2;  // 12.8 MB
    (void)ws_size; (void)in_sizes; (void)n_in; (void)out_size;

    hipMemsetAsync(cnt, 0, NR * sizeof(int), stream);
    prep_kernel<<<CNT_BLKS + CW_BLKS + FB_BLKS, 256, 0, stream>>>(tri, W, features, cnt, Wtf, featB);
    scan_part<<<SCAN_NBLK, 256, 0, stream>>>(cnt, bsum);
    scan_fused<<<SCAN_NBLK, 256, 0, stream>>>(cnt, bsum, segOff, cursor);
    scatter_kernel<<<CNT_BLKS, 256, 0, stream>>>(tri, cursor, sortedSrc);
    fused_kernel<<<FUSE_BLKS, 512, 0, stream>>>(sortedSrc, segOff, featB, Wtf, bias, out);
}